// Round 36
// baseline (5383.500 us; speedup 1.0000x reference)
//
#include <hip/hip_runtime.h>
#include <cmath>

#define B_    8
#define LS_   512
#define L_    1024
#define D_    1024
#define H_    16
#define HD_   64
#define FF_   4096
#define NL_   12
#define NTOK_ (B_*L_)

typedef __attribute__((ext_vector_type(8))) short short8;
typedef __bf16 bf16x8 __attribute__((ext_vector_type(8)));
typedef __attribute__((ext_vector_type(4))) float f32x4;
typedef unsigned short u16;

__device__ __forceinline__ u16 f2bf(float f) {
  unsigned u = __builtin_bit_cast(unsigned, f);
  unsigned r = (u + 0x7fffu + ((u >> 16) & 1u)) >> 16;
  return (u16)r;
}

__device__ __forceinline__ void load_lds16(const void* g, void* l) {
  __builtin_amdgcn_global_load_lds(
      (const __attribute__((address_space(1))) unsigned*)g,
      (__attribute__((address_space(3))) unsigned*)l, 16, 0, 0);
}

__device__ __forceinline__ void raw_barrier() {
  __builtin_amdgcn_sched_barrier(0);
  __builtin_amdgcn_s_barrier();
  __builtin_amdgcn_sched_barrier(0);
}

// ---------------- pos-embed + concat ----------------
__global__ void posadd_kernel(const float* __restrict__ sensor, const float* __restrict__ traj,
                              const float* __restrict__ pos, float* __restrict__ x) {
  int idx = blockIdx.x * blockDim.x + threadIdx.x;
  int d4 = idx & (D_/4 - 1);
  int n  = idx >> 8;
  int l  = n & (L_ - 1);
  int b  = n >> 10;
  const float* src = (l < LS_) ? (sensor + ((size_t)(b*LS_ + l))*D_)
                               : (traj   + ((size_t)(b*LS_ + l - LS_))*D_);
  float4 v = reinterpret_cast<const float4*>(src)[d4];
  float4 p = reinterpret_cast<const float4*>(pos + (size_t)l*D_)[d4];
  v.x += p.x; v.y += p.y; v.z += p.z; v.w += p.w;
  reinterpret_cast<float4*>(x + (size_t)n*D_)[d4] = v;
}

// ---------------- LayerNorm: one row per WAVE (no LDS, no barrier) ----------------
template<typename OUT>
__device__ __forceinline__ void ln_row(const float* __restrict__ x, const float* __restrict__ gam,
                                       const float* __restrict__ bet, OUT* __restrict__ out,
                                       int row, int lane) {
  const float4* xr = reinterpret_cast<const float4*>(x + (size_t)row * D_);
  float4 v[4];
  float sum = 0.f, sq = 0.f;
  #pragma unroll
  for (int i = 0; i < 4; i++) {
    v[i] = xr[lane + i*64];
    sum += v[i].x + v[i].y + v[i].z + v[i].w;
    sq  += v[i].x*v[i].x + v[i].y*v[i].y + v[i].z*v[i].z + v[i].w*v[i].w;
  }
  #pragma unroll
  for (int o = 1; o < 64; o <<= 1) {
    sum += __shfl_xor(sum, o, 64);
    sq  += __shfl_xor(sq,  o, 64);
  }
  float mean = sum * (1.0f / D_);
  float var  = sq  * (1.0f / D_) - mean * mean;
  float inv  = rsqrtf(var + 1e-5f);
  const float4* g4 = reinterpret_cast<const float4*>(gam);
  const float4* b4 = reinterpret_cast<const float4*>(bet);
  #pragma unroll
  for (int i = 0; i < 4; i++) {
    float4 g = g4[lane + i*64];
    float4 bb = b4[lane + i*64];
    float o0 = (v[i].x - mean) * inv * g.x + bb.x;
    float o1 = (v[i].y - mean) * inv * g.y + bb.y;
    float o2 = (v[i].z - mean) * inv * g.z + bb.z;
    float o3 = (v[i].w - mean) * inv * g.w + bb.w;
    if constexpr (sizeof(OUT) == 2) {
      ushort4 r; r.x = f2bf(o0); r.y = f2bf(o1); r.z = f2bf(o2); r.w = f2bf(o3);
      reinterpret_cast<ushort4*>(out + (size_t)row * D_)[lane + i*64] = r;
    } else {
      float4 r; r.x = o0; r.y = o1; r.z = o2; r.w = o3;
      reinterpret_cast<float4*>(out + (size_t)row * D_)[lane + i*64] = r;
    }
  }
}

template<typename OUT>
__global__ __launch_bounds__(256) void ln_kernel(const float* __restrict__ x,
                                                 const float* __restrict__ gam,
                                                 const float* __restrict__ bet,
                                                 OUT* __restrict__ out) {
  int w = threadIdx.x >> 6, lane = threadIdx.x & 63;
  ln_row<OUT>(x, gam, bet, out, (blockIdx.x << 2) + w, lane);
}

// ---------------- fused weight-cast + LN1 (one dispatch per layer) ----------------
#define N0_ (3*D_*D_/4)
#define N1_ (D_*D_/4)
#define N2_ (FF_*D_/4)
#define N3_ (D_*FF_/4)
#define NCAST_ ((N0_ + N1_ + N2_ + N3_) / 256)
__global__ __launch_bounds__(256) void castln_kernel(const float* __restrict__ s0, const float* __restrict__ s1,
                                                     const float* __restrict__ s2, const float* __restrict__ s3,
                                                     u16* __restrict__ out,
                                                     const float* __restrict__ x, const float* __restrict__ gam,
                                                     const float* __restrict__ bet, u16* __restrict__ h) {
  int blk = blockIdx.x;
  if (blk < NCAST_) {
    int i = blk * 256 + threadIdx.x;
    const float* src;
    int j = i;
    if (j < N0_) { src = s0; }
    else if ((j -= N0_) < N1_) { src = s1; }
    else if ((j -= N1_) < N2_) { src = s2; }
    else { j -= N2_; src = s3; }
    float4 v = reinterpret_cast<const float4*>(src)[j];
    ushort4 r; r.x = f2bf(v.x); r.y = f2bf(v.y); r.z = f2bf(v.z); r.w = f2bf(v.w);
    reinterpret_cast<ushort4*>(out)[i] = r;
  } else {
    int w = threadIdx.x >> 6, lane = threadIdx.x & 63;
    int row = ((blk - NCAST_) << 2) + w;
    ln_row<u16>(x, gam, bet, h, row, lane);
  }
}

// ============ 256x128 GEMM (QKV / FFN1): 8 waves (4Mx2N), 2-buf ============
// Per-wave structure identical to the proven 128^2 kernel. x-major block order.
// Zero-conflict 16B-block swizzle blk ^= (row>>1)&3, inverse on global source.
// EPI 1: gelu->bf16; EPI 3: QKV routing.
template<int EPI>
__global__ __launch_bounds__(512) void gemm256x128_kernel(const u16* __restrict__ A, const u16* __restrict__ W,
                                                          const float* __restrict__ bias, u16* __restrict__ Cbf,
                                                          u16* __restrict__ Kt, u16* __restrict__ Vt,
                                                          int M, int K, int gx) {
  __shared__ u16 lsA[2][8192];   // 256 x 32
  __shared__ u16 lsB[2][4096];   // 128 x 32
  int tid = threadIdx.x, lane = tid & 63, w = tid >> 6;
  int wr = w >> 1, wc = w & 1;                 // 4 x 2 wave grid
  int bid = blockIdx.x, bx = bid % gx, by = bid / gx;
  int row0 = bx << 8, col0 = by << 7;
  int l15 = lane & 15, l4 = lane >> 4;

  const u16 *pA[2], *pB;
  int dcA[2], dcB;
  #pragma unroll
  for (int i = 0; i < 2; i++) {
    int c = w*2 + i;
    int rt = c*16 + (lane >> 2);
    int g  = (lane & 3) ^ ((rt >> 1) & 3);
    pA[i] = A + (size_t)(row0 + rt) * K + g * 8;
    dcA[i] = c * 512;
  }
  {
    int rt = w*16 + (lane >> 2);
    int g  = (lane & 3) ^ ((rt >> 1) & 3);
    pB = W + (size_t)(col0 + rt) * K + g * 8;
    dcB = w * 512;
  }

  f32x4 acc[4][4] = {};
  int nt = K >> 5;

  #pragma unroll
  for (int i = 0; i < 2; i++) load_lds16(pA[i], &lsA[0][dcA[i]]);
  load_lds16(pB, &lsB[0][dcB]);
  asm volatile("s_waitcnt vmcnt(0)" ::: "memory");
  raw_barrier();

  for (int t = 0; t < nt; t++) {
    int cur = t & 1;
    if (t + 1 < nt) {
      int kq = (t + 1) << 5;
      #pragma unroll
      for (int i = 0; i < 2; i++) load_lds16(pA[i] + kq, &lsA[cur^1][dcA[i]]);
      load_lds16(pB + kq, &lsB[cur^1][dcB]);
    }
    bf16x8 af[4], bfr[4];
    #pragma unroll
    for (int m = 0; m < 4; m++) {
      int row = wr * 64 + m * 16 + l15;
      int blk = l4 ^ ((row >> 1) & 3);
      af[m] = *reinterpret_cast<const bf16x8*>(&lsA[cur][row * 32 + blk * 8]);
    }
    #pragma unroll
    for (int n = 0; n < 4; n++) {
      int row = wc * 64 + n * 16 + l15;
      int blk = l4 ^ ((row >> 1) & 3);
      bfr[n] = *reinterpret_cast<const bf16x8*>(&lsB[cur][row * 32 + blk * 8]);
    }
    __builtin_amdgcn_s_setprio(1);
    #pragma unroll
    for (int m = 0; m < 4; m++)
      #pragma unroll
      for (int n = 0; n < 4; n++)
        acc[m][n] = __builtin_amdgcn_mfma_f32_16x16x32_bf16(af[m], bfr[n], acc[m][n], 0, 0, 0);
    __builtin_amdgcn_s_setprio(0);
    asm volatile("s_waitcnt vmcnt(0)" ::: "memory");
    raw_barrier();
  }

  int rb = row0 + wr*64 + (l4 << 2);
  int cb = col0 + wc*64 + l15;
  #pragma unroll
  for (int m = 0; m < 4; m++) {
    #pragma unroll
    for (int n = 0; n < 4; n++) {
      int col = cb + n * 16;
      float bv = bias[col];
      #pragma unroll
      for (int r = 0; r < 4; r++) {
        int row = rb + m * 16 + r;
        float v = acc[m][n][r] + bv;
        if constexpr (EPI == 1) {
          float gl = 0.5f * v * (1.0f + erff(v * 0.70710678118f));
          Cbf[(size_t)row * M + col] = f2bf(gl);
        } else {
          int bb = row >> 10, ll = row & 1023;
          int tile = ll >> 6, kv = ll & 63;
          if (col0 < 1024) {
            Cbf[(size_t)row * 1024 + col] = f2bf(v);
          } else if (col0 < 2048) {
            int cc = col - 1024;
            int hh = cc >> 6, d = cc & 63;
            size_t base = (((size_t)(bb*16 + hh)*16 + tile) << 12);
            Kt[base + kv*64 + (d ^ ((kv & 7) << 3))] = f2bf(v);
          } else {
            int cc = col - 2048;
            int hh = cc >> 6, d = cc & 63;
            int pos = ((kv & 15) << 2) | (((kv >> 5) & 1) << 1) | ((kv >> 4) & 1);
            size_t base = (((size_t)(bb*16 + hh)*16 + tile) << 12);
            Vt[base + d*64 + (pos ^ ((d & 7) << 3))] = f2bf(v);
          }
        }
      }
    }
  }
}

// ---------------- 128x128 MFMA GEMM (proj / FFN2), 3-buf depth-2, residual ----------------
__global__ __launch_bounds__(256) void gemm_kernel(const u16* __restrict__ A, const u16* __restrict__ W,
                                                   const float* __restrict__ bias,
                                                   float* __restrict__ resid,
                                                   int M, int K, int gx) {
  __shared__ u16 lsA[3][4096];
  __shared__ u16 lsB[3][4096];
  int tid = threadIdx.x;
  int lane = tid & 63;
  int w = tid >> 6;
  int wg = blockIdx.x;
  int bx = wg % gx, by = wg / gx;
  int row0 = bx << 7;
  int col0 = by << 7;
  int wr = w >> 1, wc = w & 1;

  const u16* pA[2]; const u16* pB[2];
  int dstc[2];
  #pragma unroll
  for (int i = 0; i < 2; i++) {
    int c = w * 2 + i;
    int rt = c * 16 + (lane >> 2);
    int g  = (lane & 3) ^ ((rt >> 1) & 3);
    pA[i] = A + (size_t)(row0 + rt) * K + g * 8;
    pB[i] = W + (size_t)(col0 + rt) * K + g * 8;
    dstc[i] = c * 512;
  }

  f32x4 acc[4][4] = {};
  int nt = K >> 5;

  #pragma unroll
  for (int i = 0; i < 2; i++) {
    load_lds16(pA[i], &lsA[0][dstc[i]]);
    load_lds16(pB[i], &lsB[0][dstc[i]]);
  }
  #pragma unroll
  for (int i = 0; i < 2; i++) {
    load_lds16(pA[i] + 32, &lsA[1][dstc[i]]);
    load_lds16(pB[i] + 32, &lsB[1][dstc[i]]);
  }
  asm volatile("s_waitcnt vmcnt(4)" ::: "memory");
  raw_barrier();

  int cur = 0;
  for (int t = 0; t < nt; t++) {
    int ib = (cur == 0) ? 2 : cur - 1;
    if (t + 2 < nt) {
      int kq = (t + 2) << 5;
      #pragma unroll
      for (int i = 0; i < 2; i++) {
        load_lds16(pA[i] + kq, &lsA[ib][dstc[i]]);
        load_lds16(pB[i] + kq, &lsB[ib][dstc[i]]);
      }
    }
    bf16x8 af[4], bfr[4];
    #pragma unroll
    for (int m = 0; m < 4; m++) {
      int row = wr * 64 + m * 16 + (lane & 15);
      int blk = (lane >> 4) ^ ((row >> 1) & 3);
      af[m] = *reinterpret_cast<const bf16x8*>(&lsA[cur][row * 32 + blk * 8]);
    }
    #pragma unroll
    for (int n = 0; n < 4; n++) {
      int row = wc * 64 + n * 16 + (lane & 15);
      int blk = (lane >> 4) ^ ((row >> 1) & 3);
      bfr[n] = *reinterpret_cast<const bf16x8*>(&lsB[cur][row * 32 + blk * 8]);
    }
    __builtin_amdgcn_s_setprio(1);
    #pragma unroll
    for (int m = 0; m < 4; m++)
      #pragma unroll
      for (int n = 0; n < 4; n++)
        acc[m][n] = __builtin_amdgcn_mfma_f32_16x16x32_bf16(af[m], bfr[n], acc[m][n], 0, 0, 0);
    __builtin_amdgcn_s_setprio(0);
    if (t + 2 < nt) {
      asm volatile("s_waitcnt vmcnt(4)" ::: "memory");
    } else {
      asm volatile("s_waitcnt vmcnt(0)" ::: "memory");
    }
    raw_barrier();
    cur = (cur == 2) ? 0 : cur + 1;
  }

  int rb = row0 + wr*64 + ((lane >> 4) << 2);
  int cb = col0 + wc*64 + (lane & 15);
  #pragma unroll
  for (int m = 0; m < 4; m++) {
    #pragma unroll
    for (int n = 0; n < 4; n++) {
      int col = cb + n * 16;
      float bv = bias[col];
      #pragma unroll
      for (int r = 0; r < 4; r++) {
        int row = rb + m * 16 + r;
        resid[(size_t)row * M + col] += acc[m][n][r] + bv;
      }
    }
  }
}

// ---------------- flash attention, prefix-causal ----------------
__global__ __launch_bounds__(256) void attn_kernel(const u16* __restrict__ Qb,
                                                   const u16* __restrict__ Kt,
                                                   const u16* __restrict__ Vt,
                                                   u16* __restrict__ o) {
  __shared__ u16 KV[2][2][4096];
  __shared__ unsigned Ps[4][512];
  int tid = threadIdx.x;
  int lane = tid & 63;
  int wq = tid >> 6;
  int tile = blockIdx.x & 15;
  int bh = blockIdx.x >> 4;
  int b = bh >> 4;
  int h = bh & 15;
  int q0b = tile << 6;
  int q0 = q0b + wq * 16;
  size_t tok0 = (size_t)b * L_;
  int l15 = lane & 15;
  int l4  = lane >> 4;

  bf16x8 aq[2];
  #pragma unroll
  for (int kk = 0; kk < 2; kk++)
    aq[kk] = *reinterpret_cast<const bf16x8*>(Qb + (tok0 + q0 + l15) * 1024 + h * 64 + kk * 32 + (l4 << 3));

  f32x4 acc[4] = {};
  float mrow[4] = {-INFINITY, -INFINITY, -INFINITY, -INFINITY};
  float lrow[4] = {0.f, 0.f, 0.f, 0.f};
  int nkv_w = (q0b >= LS_) ? (q0 + 16) : LS_;
  bool causal = (q0b >= LS_);
  int ntiles = (q0b >= LS_) ? (tile + 1) : (LS_ >> 6);

  const u16* Kbh = Kt + (((size_t)bh) << 16);
  const u16* Vbh = Vt + (((size_t)bh) << 16);

  int soff = wq * 1024 + lane * 8;
  int doff = wq * 1024;

  #pragma unroll
  for (int i = 0; i < 2; i++) {
    load_lds16(Kbh + soff + i*512, &KV[0][0][doff + i*512]);
    load_lds16(Vbh + soff + i*512, &KV[0][1][doff + i*512]);
  }
  asm volatile("s_waitcnt vmcnt(0)" ::: "memory");
  raw_barrier();

  for (int t = 0; t < ntiles; t++) {
    int cur = t & 1;
    if (t + 1 < ntiles) {
      const u16* kn = Kbh + ((size_t)(t+1) << 12);
      const u16* vn = Vbh + ((size_t)(t+1) << 12);
      #pragma unroll
      for (int i = 0; i < 2; i++) {
        load_lds16(kn + soff + i*512, &KV[cur^1][0][doff + i*512]);
        load_lds16(vn + soff + i*512, &KV[cur^1][1][doff + i*512]);
      }
    }
    int kv0 = t << 6;
    if (kv0 < nkv_w) {
      const u16* Kl = &KV[cur][0][0];
      const u16* Vl = &KV[cur][1][0];
      f32x4 sf[4];
      __builtin_amdgcn_s_setprio(1);
      #pragma unroll
      for (int t4 = 0; t4 < 4; t4++) {
        f32x4 s = {0.f, 0.f, 0.f, 0.f};
        int kvl = t4*16 + l15;
        #pragma unroll
        for (int kk = 0; kk < 2; kk++) {
          bf16x8 bk = *reinterpret_cast<const bf16x8*>(&Kl[kvl*64 + ((kk*32 + l4*8) ^ ((l15 & 7) << 3))]);
          s = __builtin_amdgcn_mfma_f32_16x16x32_bf16(aq[kk], bk, s, 0, 0, 0);
        }
        sf[t4] = s * 0.125f;
      }
      __builtin_amdgcn_s_setprio(0);
      if (causal && (kv0 + 63 > q0)) {
        #pragma unroll
        for (int t4 = 0; t4 < 4; t4++) {
          int kvg = kv0 + t4*16 + l15;
          #pragma unroll
          for (int r = 0; r < 4; r++) {
            int qg = q0 + (l4 << 2) + r;
            if (kvg > qg) sf[t4][r] = -INFINITY;
          }
        }
      }
      float pv[4][4];
      #pragma unroll
      for (int r = 0; r < 4; r++) {
        float mx = fmaxf(fmaxf(sf[0][r], sf[1][r]), fmaxf(sf[2][r], sf[3][r]));
        #pragma unroll
        for (int off = 1; off < 16; off <<= 1) mx = fmaxf(mx, __shfl_xor(mx, off, 64));
        float mnew = fmaxf(mrow[r], mx);
        float alpha = __expf(mrow[r] - mnew);
        mrow[r] = mnew;
        float psum = 0.f;
        #pragma unroll
        for (int t4 = 0; t4 < 4; t4++) {
          float p = __expf(sf[t4][r] - mnew);
          pv[t4][r] = p;
          psum += p;
        }
        #pragma unroll
        for (int off = 1; off < 16; off <<= 1) psum += __shfl_xor(psum, off, 64);
        lrow[r] = lrow[r] * alpha + psum;
        #pragma unroll
        for (int h4 = 0; h4 < 4; h4++) acc[h4][r] *= alpha;
      }
      #pragma unroll
      for (int r = 0; r < 4; r++) {
        int ql = l4*4 + r;
        unsigned wA = (unsigned)f2bf(pv[0][r]) | ((unsigned)f2bf(pv[1][r]) << 16);
        unsigned wB = (unsigned)f2bf(pv[2][r]) | ((unsigned)f2bf(pv[3][r]) << 16);
        int xo = (ql & 7) << 2;
        Ps[wq][ql*32 + ((2*l15)     ^ xo)] = wA;
        Ps[wq][ql*32 + ((2*l15 + 1) ^ xo)] = wB;
      }
      __builtin_amdgcn_s_setprio(1);
      #pragma unroll
      for (int h4 = 0; h4 < 4; h4++) {
        int dl = h4*16 + l15;
        #pragma unroll
        for (int kk = 0; kk < 2; kk++) {
          bf16x8 pa = *reinterpret_cast<const bf16x8*>(
              (const u16*)&Ps[wq][0] + l15*64 + ((kk*32 + l4*8) ^ ((l15 & 7) << 3)));
          bf16x8 vb = *reinterpret_cast<const bf16x8*>(&Vl[dl*64 + ((kk*32 + l4*8) ^ ((l15 & 7) << 3))]);
          acc[h4] = __builtin_amdgcn_mfma_f32_16x16x32_bf16(pa, vb, acc[h4], 0, 0, 0);
        }
      }
      __builtin_amdgcn_s_setprio(0);
    }
    asm volatile("s_waitcnt vmcnt(0)" ::: "memory");
    raw_barrier();
  }
  #pragma unroll
  for (int h4 = 0; h4 < 4; h4++) {
    #pragma unroll
    for (int r = 0; r < 4; r++) {
      int row = q0 + (l4 << 2) + r;
      float ov = acc[h4][r] / lrow[r];
      o[(tok0 + row) * 1024 + h * 64 + h4*16 + l15] = f2bf(ov);
    }
  }
}

extern "C" void kernel_launch(void* const* d_in, const int* in_sizes, int n_in,
                              void* d_out, int out_size, void* d_ws, size_t ws_size,
                              hipStream_t stream) {
  (void)in_sizes; (void)n_in; (void)out_size; (void)ws_size;
  const float* sensor = (const float*)d_in[0];
  const float* traj   = (const float*)d_in[1];
  const float* pos    = (const float*)d_in[2];
  const float* ln1_s  = (const float*)d_in[3];
  const float* ln1_b  = (const float*)d_in[4];
  const float* qkv_w  = (const float*)d_in[5];
  const float* qkv_b  = (const float*)d_in[6];
  const float* out_w  = (const float*)d_in[7];
  const float* out_b  = (const float*)d_in[8];
  const float* ln2_s  = (const float*)d_in[9];
  const float* ln2_b  = (const float*)d_in[10];
  const float* w1     = (const float*)d_in[11];
  const float* b1     = (const float*)d_in[12];
  const float* w2     = (const float*)d_in[13];
  const float* b2     = (const float*)d_in[14];
  const float* fln_s  = (const float*)d_in[15];
  const float* fln_b  = (const float*)d_in[16];

  char* ws = (char*)d_ws;
  size_t off = 0;
  float* x  = (float*)(ws + off); off += (size_t)NTOK_ * D_ * 4;
  u16* h    = (u16*)(ws + off);   off += (size_t)NTOK_ * D_ * 2;
  u16* Qb   = (u16*)(ws + off);   off += (size_t)NTOK_ * D_ * 2;
  u16* Ktl  = (u16*)(ws + off);   off += (size_t)NTOK_ * D_ * 2;
  u16* Vtl  = (u16*)(ws + off);   off += (size_t)NTOK_ * D_ * 2;
  u16* ob   = (u16*)(ws + off);   off += (size_t)NTOK_ * D_ * 2;
  u16* ub   = (u16*)(ws + off);   off += (size_t)NTOK_ * FF_ * 2;
  u16* wb   = (u16*)(ws + off);   off += (size_t)(3*D_*D_ + D_*D_ + FF_*D_ + D_*FF_) * 2;
  u16* wqkv = wb;
  u16* wout = wqkv + (size_t)3*D_*D_;
  u16* ww1  = wout + (size_t)D_*D_;
  u16* ww2  = ww1  + (size_t)FF_*D_;

  posadd_kernel<<<NTOK_ * D_ / 1024, 256, 0, stream>>>(sensor, traj, pos, x);

  for (int i = 0; i < NL_; i++) {
    castln_kernel<<<NCAST_ + NTOK_/4, 256, 0, stream>>>(
        qkv_w + (size_t)i*3*D_*D_, out_w + (size_t)i*D_*D_,
        w1 + (size_t)i*FF_*D_, w2 + (size_t)i*D_*FF_, wb,
        x, ln1_s + i*D_, ln1_b + i*D_, h);
    gemm256x128_kernel<3><<<32*24, 512, 0, stream>>>(h, wqkv, qkv_b + (size_t)i*3*D_, Qb, Ktl, Vtl, 3*D_, D_, 32);
    attn_kernel<<<B_*H_*(L_/64), 256, 0, stream>>>(Qb, Ktl, Vtl, ob);
    gemm_kernel<<<64*8, 256, 0, stream>>>(ob, wout, out_b + (size_t)i*D_, x, D_, D_, 64);
    ln_kernel<u16><<<NTOK_/4, 256, 0, stream>>>(x, ln2_s + i*D_, ln2_b + i*D_, h);
    gemm256x128_kernel<1><<<32*32, 512, 0, stream>>>(h, ww1, b1 + (size_t)i*FF_, ub, nullptr, nullptr, FF_, D_, 32);
    gemm_kernel<<<64*8, 256, 0, stream>>>(ub, ww2, b2 + (size_t)i*D_, x, D_, FF_, 64);
  }
  ln_kernel<float><<<NTOK_/4, 256, 0, stream>>>(x, fln_s, fln_b, (float*)d_out);
}

// Round 37
// 5336.938 us; speedup vs baseline: 1.0087x; 1.0087x over previous
//
#include <hip/hip_runtime.h>
#include <cmath>

#define B_    8
#define LS_   512
#define L_    1024
#define D_    1024
#define H_    16
#define HD_   64
#define FF_   4096
#define NL_   12
#define NTOK_ (B_*L_)

typedef __attribute__((ext_vector_type(8))) short short8;
typedef __bf16 bf16x8 __attribute__((ext_vector_type(8)));
typedef __attribute__((ext_vector_type(4))) float f32x4;
typedef unsigned short u16;

__device__ __forceinline__ u16 f2bf(float f) {
  unsigned u = __builtin_bit_cast(unsigned, f);
  unsigned r = (u + 0x7fffu + ((u >> 16) & 1u)) >> 16;
  return (u16)r;
}

__device__ __forceinline__ void load_lds16(const void* g, void* l) {
  __builtin_amdgcn_global_load_lds(
      (const __attribute__((address_space(1))) unsigned*)g,
      (__attribute__((address_space(3))) unsigned*)l, 16, 0, 0);
}

__device__ __forceinline__ void raw_barrier() {
  __builtin_amdgcn_sched_barrier(0);
  __builtin_amdgcn_s_barrier();
  __builtin_amdgcn_sched_barrier(0);
}

// ---------------- pos-embed + concat ----------------
__global__ void posadd_kernel(const float* __restrict__ sensor, const float* __restrict__ traj,
                              const float* __restrict__ pos, float* __restrict__ x) {
  int idx = blockIdx.x * blockDim.x + threadIdx.x;
  int d4 = idx & (D_/4 - 1);
  int n  = idx >> 8;
  int l  = n & (L_ - 1);
  int b  = n >> 10;
  const float* src = (l < LS_) ? (sensor + ((size_t)(b*LS_ + l))*D_)
                               : (traj   + ((size_t)(b*LS_ + l - LS_))*D_);
  float4 v = reinterpret_cast<const float4*>(src)[d4];
  float4 p = reinterpret_cast<const float4*>(pos + (size_t)l*D_)[d4];
  v.x += p.x; v.y += p.y; v.z += p.z; v.w += p.w;
  reinterpret_cast<float4*>(x + (size_t)n*D_)[d4] = v;
}

// ---------------- LayerNorm: one row per WAVE (no LDS, no barrier) ----------------
template<typename OUT>
__device__ __forceinline__ void ln_row(const float* __restrict__ x, const float* __restrict__ gam,
                                       const float* __restrict__ bet, OUT* __restrict__ out,
                                       int row, int lane) {
  const float4* xr = reinterpret_cast<const float4*>(x + (size_t)row * D_);
  float4 v[4];
  float sum = 0.f, sq = 0.f;
  #pragma unroll
  for (int i = 0; i < 4; i++) {
    v[i] = xr[lane + i*64];
    sum += v[i].x + v[i].y + v[i].z + v[i].w;
    sq  += v[i].x*v[i].x + v[i].y*v[i].y + v[i].z*v[i].z + v[i].w*v[i].w;
  }
  #pragma unroll
  for (int o = 1; o < 64; o <<= 1) {
    sum += __shfl_xor(sum, o, 64);
    sq  += __shfl_xor(sq,  o, 64);
  }
  float mean = sum * (1.0f / D_);
  float var  = sq  * (1.0f / D_) - mean * mean;
  float inv  = rsqrtf(var + 1e-5f);
  const float4* g4 = reinterpret_cast<const float4*>(gam);
  const float4* b4 = reinterpret_cast<const float4*>(bet);
  #pragma unroll
  for (int i = 0; i < 4; i++) {
    float4 g = g4[lane + i*64];
    float4 bb = b4[lane + i*64];
    float o0 = (v[i].x - mean) * inv * g.x + bb.x;
    float o1 = (v[i].y - mean) * inv * g.y + bb.y;
    float o2 = (v[i].z - mean) * inv * g.z + bb.z;
    float o3 = (v[i].w - mean) * inv * g.w + bb.w;
    if constexpr (sizeof(OUT) == 2) {
      ushort4 r; r.x = f2bf(o0); r.y = f2bf(o1); r.z = f2bf(o2); r.w = f2bf(o3);
      reinterpret_cast<ushort4*>(out + (size_t)row * D_)[lane + i*64] = r;
    } else {
      float4 r; r.x = o0; r.y = o1; r.z = o2; r.w = o3;
      reinterpret_cast<float4*>(out + (size_t)row * D_)[lane + i*64] = r;
    }
  }
}

template<typename OUT>
__global__ __launch_bounds__(256) void ln_kernel(const float* __restrict__ x,
                                                 const float* __restrict__ gam,
                                                 const float* __restrict__ bet,
                                                 OUT* __restrict__ out) {
  int w = threadIdx.x >> 6, lane = threadIdx.x & 63;
  ln_row<OUT>(x, gam, bet, out, (blockIdx.x << 2) + w, lane);
}

// ---------------- fused weight-cast + LN1 (one dispatch per layer) ----------------
#define N0_ (3*D_*D_/4)
#define N1_ (D_*D_/4)
#define N2_ (FF_*D_/4)
#define N3_ (D_*FF_/4)
#define NCAST_ ((N0_ + N1_ + N2_ + N3_) / 256)
__global__ __launch_bounds__(256) void castln_kernel(const float* __restrict__ s0, const float* __restrict__ s1,
                                                     const float* __restrict__ s2, const float* __restrict__ s3,
                                                     u16* __restrict__ out,
                                                     const float* __restrict__ x, const float* __restrict__ gam,
                                                     const float* __restrict__ bet, u16* __restrict__ h) {
  int blk = blockIdx.x;
  if (blk < NCAST_) {
    int i = blk * 256 + threadIdx.x;
    const float* src;
    int j = i;
    if (j < N0_) { src = s0; }
    else if ((j -= N0_) < N1_) { src = s1; }
    else if ((j -= N1_) < N2_) { src = s2; }
    else { j -= N2_; src = s3; }
    float4 v = reinterpret_cast<const float4*>(src)[j];
    ushort4 r; r.x = f2bf(v.x); r.y = f2bf(v.y); r.z = f2bf(v.z); r.w = f2bf(v.w);
    reinterpret_cast<ushort4*>(out)[i] = r;
  } else {
    int w = threadIdx.x >> 6, lane = threadIdx.x & 63;
    int row = ((blk - NCAST_) << 2) + w;
    ln_row<u16>(x, gam, bet, h, row, lane);
  }
}

// ============ 256x128 GEMM (QKV / FFN1): 8 waves (4Mx2N), 2-buf ============
// Per-wave structure identical to the proven 128^2 kernel. x-major block order.
// Zero-conflict 16B-block swizzle blk ^= (row>>1)&3, inverse on global source.
// EPI 1: gelu->bf16; EPI 3: QKV routing.
template<int EPI>
__global__ __launch_bounds__(512) void gemm256x128_kernel(const u16* __restrict__ A, const u16* __restrict__ W,
                                                          const float* __restrict__ bias, u16* __restrict__ Cbf,
                                                          u16* __restrict__ Kt, u16* __restrict__ Vt,
                                                          int M, int K, int gx) {
  __shared__ u16 lsA[2][8192];   // 256 x 32
  __shared__ u16 lsB[2][4096];   // 128 x 32
  int tid = threadIdx.x, lane = tid & 63, w = tid >> 6;
  int wr = w >> 1, wc = w & 1;                 // 4 x 2 wave grid
  int bid = blockIdx.x, bx = bid % gx, by = bid / gx;
  int row0 = bx << 8, col0 = by << 7;
  int l15 = lane & 15, l4 = lane >> 4;

  const u16 *pA[2], *pB;
  int dcA[2], dcB;
  #pragma unroll
  for (int i = 0; i < 2; i++) {
    int c = w*2 + i;
    int rt = c*16 + (lane >> 2);
    int g  = (lane & 3) ^ ((rt >> 1) & 3);
    pA[i] = A + (size_t)(row0 + rt) * K + g * 8;
    dcA[i] = c * 512;
  }
  {
    int rt = w*16 + (lane >> 2);
    int g  = (lane & 3) ^ ((rt >> 1) & 3);
    pB = W + (size_t)(col0 + rt) * K + g * 8;
    dcB = w * 512;
  }

  f32x4 acc[4][4] = {};
  int nt = K >> 5;

  #pragma unroll
  for (int i = 0; i < 2; i++) load_lds16(pA[i], &lsA[0][dcA[i]]);
  load_lds16(pB, &lsB[0][dcB]);
  asm volatile("s_waitcnt vmcnt(0)" ::: "memory");
  raw_barrier();

  for (int t = 0; t < nt; t++) {
    int cur = t & 1;
    if (t + 1 < nt) {
      int kq = (t + 1) << 5;
      #pragma unroll
      for (int i = 0; i < 2; i++) load_lds16(pA[i] + kq, &lsA[cur^1][dcA[i]]);
      load_lds16(pB + kq, &lsB[cur^1][dcB]);
    }
    bf16x8 af[4], bfr[4];
    #pragma unroll
    for (int m = 0; m < 4; m++) {
      int row = wr * 64 + m * 16 + l15;
      int blk = l4 ^ ((row >> 1) & 3);
      af[m] = *reinterpret_cast<const bf16x8*>(&lsA[cur][row * 32 + blk * 8]);
    }
    #pragma unroll
    for (int n = 0; n < 4; n++) {
      int row = wc * 64 + n * 16 + l15;
      int blk = l4 ^ ((row >> 1) & 3);
      bfr[n] = *reinterpret_cast<const bf16x8*>(&lsB[cur][row * 32 + blk * 8]);
    }
    __builtin_amdgcn_s_setprio(1);
    #pragma unroll
    for (int m = 0; m < 4; m++)
      #pragma unroll
      for (int n = 0; n < 4; n++)
        acc[m][n] = __builtin_amdgcn_mfma_f32_16x16x32_bf16(af[m], bfr[n], acc[m][n], 0, 0, 0);
    __builtin_amdgcn_s_setprio(0);
    asm volatile("s_waitcnt vmcnt(0)" ::: "memory");
    raw_barrier();
  }

  int rb = row0 + wr*64 + (l4 << 2);
  int cb = col0 + wc*64 + l15;
  #pragma unroll
  for (int m = 0; m < 4; m++) {
    #pragma unroll
    for (int n = 0; n < 4; n++) {
      int col = cb + n * 16;
      float bv = bias[col];
      #pragma unroll
      for (int r = 0; r < 4; r++) {
        int row = rb + m * 16 + r;
        float v = acc[m][n][r] + bv;
        if constexpr (EPI == 1) {
          float gl = 0.5f * v * (1.0f + erff(v * 0.70710678118f));
          Cbf[(size_t)row * M + col] = f2bf(gl);
        } else {
          int bb = row >> 10, ll = row & 1023;
          int tile = ll >> 6, kv = ll & 63;
          if (col0 < 1024) {
            Cbf[(size_t)row * 1024 + col] = f2bf(v);
          } else if (col0 < 2048) {
            int cc = col - 1024;
            int hh = cc >> 6, d = cc & 63;
            size_t base = (((size_t)(bb*16 + hh)*16 + tile) << 12);
            Kt[base + kv*64 + (d ^ ((kv & 7) << 3))] = f2bf(v);
          } else {
            int cc = col - 2048;
            int hh = cc >> 6, d = cc & 63;
            int pos = ((kv & 15) << 2) | (((kv >> 5) & 1) << 1) | ((kv >> 4) & 1);
            size_t base = (((size_t)(bb*16 + hh)*16 + tile) << 12);
            Vt[base + d*64 + (pos ^ ((d & 7) << 3))] = f2bf(v);
          }
        }
      }
    }
  }
}

// ---------------- 128x128 MFMA GEMM (proj / FFN2), 3-buf depth-2, residual ----------------
__global__ __launch_bounds__(256) void gemm_kernel(const u16* __restrict__ A, const u16* __restrict__ W,
                                                   const float* __restrict__ bias,
                                                   float* __restrict__ resid,
                                                   int M, int K, int gx) {
  __shared__ u16 lsA[3][4096];
  __shared__ u16 lsB[3][4096];
  int tid = threadIdx.x;
  int lane = tid & 63;
  int w = tid >> 6;
  int wg = blockIdx.x;
  int bx = wg % gx, by = wg / gx;
  int row0 = bx << 7;
  int col0 = by << 7;
  int wr = w >> 1, wc = w & 1;

  const u16* pA[2]; const u16* pB[2];
  int dstc[2];
  #pragma unroll
  for (int i = 0; i < 2; i++) {
    int c = w * 2 + i;
    int rt = c * 16 + (lane >> 2);
    int g  = (lane & 3) ^ ((rt >> 1) & 3);
    pA[i] = A + (size_t)(row0 + rt) * K + g * 8;
    pB[i] = W + (size_t)(col0 + rt) * K + g * 8;
    dstc[i] = c * 512;
  }

  f32x4 acc[4][4] = {};
  int nt = K >> 5;

  #pragma unroll
  for (int i = 0; i < 2; i++) {
    load_lds16(pA[i], &lsA[0][dstc[i]]);
    load_lds16(pB[i], &lsB[0][dstc[i]]);
  }
  #pragma unroll
  for (int i = 0; i < 2; i++) {
    load_lds16(pA[i] + 32, &lsA[1][dstc[i]]);
    load_lds16(pB[i] + 32, &lsB[1][dstc[i]]);
  }
  asm volatile("s_waitcnt vmcnt(4)" ::: "memory");
  raw_barrier();

  int cur = 0;
  for (int t = 0; t < nt; t++) {
    int ib = (cur == 0) ? 2 : cur - 1;
    if (t + 2 < nt) {
      int kq = (t + 2) << 5;
      #pragma unroll
      for (int i = 0; i < 2; i++) {
        load_lds16(pA[i] + kq, &lsA[ib][dstc[i]]);
        load_lds16(pB[i] + kq, &lsB[ib][dstc[i]]);
      }
    }
    bf16x8 af[4], bfr[4];
    #pragma unroll
    for (int m = 0; m < 4; m++) {
      int row = wr * 64 + m * 16 + (lane & 15);
      int blk = (lane >> 4) ^ ((row >> 1) & 3);
      af[m] = *reinterpret_cast<const bf16x8*>(&lsA[cur][row * 32 + blk * 8]);
    }
    #pragma unroll
    for (int n = 0; n < 4; n++) {
      int row = wc * 64 + n * 16 + (lane & 15);
      int blk = (lane >> 4) ^ ((row >> 1) & 3);
      bfr[n] = *reinterpret_cast<const bf16x8*>(&lsB[cur][row * 32 + blk * 8]);
    }
    __builtin_amdgcn_s_setprio(1);
    #pragma unroll
    for (int m = 0; m < 4; m++)
      #pragma unroll
      for (int n = 0; n < 4; n++)
        acc[m][n] = __builtin_amdgcn_mfma_f32_16x16x32_bf16(af[m], bfr[n], acc[m][n], 0, 0, 0);
    __builtin_amdgcn_s_setprio(0);
    if (t + 2 < nt) {
      asm volatile("s_waitcnt vmcnt(4)" ::: "memory");
    } else {
      asm volatile("s_waitcnt vmcnt(0)" ::: "memory");
    }
    raw_barrier();
    cur = (cur == 2) ? 0 : cur + 1;
  }

  int rb = row0 + wr*64 + ((lane >> 4) << 2);
  int cb = col0 + wc*64 + (lane & 15);
  #pragma unroll
  for (int m = 0; m < 4; m++) {
    #pragma unroll
    for (int n = 0; n < 4; n++) {
      int col = cb + n * 16;
      float bv = bias[col];
      #pragma unroll
      for (int r = 0; r < 4; r++) {
        int row = rb + m * 16 + r;
        resid[(size_t)row * M + col] += acc[m][n][r] + bv;
      }
    }
  }
}

// ---------------- flash attention, prefix-causal ----------------
__global__ __launch_bounds__(256) void attn_kernel(const u16* __restrict__ Qb,
                                                   const u16* __restrict__ Kt,
                                                   const u16* __restrict__ Vt,
                                                   u16* __restrict__ o) {
  __shared__ u16 KV[2][2][4096];
  __shared__ unsigned Ps[4][512];
  int tid = threadIdx.x;
  int lane = tid & 63;
  int wq = tid >> 6;
  int tile = blockIdx.x & 15;
  int bh = blockIdx.x >> 4;
  int b = bh >> 4;
  int h = bh & 15;
  int q0b = tile << 6;
  int q0 = q0b + wq * 16;
  size_t tok0 = (size_t)b * L_;
  int l15 = lane & 15;
  int l4  = lane >> 4;

  bf16x8 aq[2];
  #pragma unroll
  for (int kk = 0; kk < 2; kk++)
    aq[kk] = *reinterpret_cast<const bf16x8*>(Qb + (tok0 + q0 + l15) * 1024 + h * 64 + kk * 32 + (l4 << 3));

  f32x4 acc[4] = {};
  float mrow[4] = {-INFINITY, -INFINITY, -INFINITY, -INFINITY};
  float lrow[4] = {0.f, 0.f, 0.f, 0.f};
  int nkv_w = (q0b >= LS_) ? (q0 + 16) : LS_;
  bool causal = (q0b >= LS_);
  int ntiles = (q0b >= LS_) ? (tile + 1) : (LS_ >> 6);

  const u16* Kbh = Kt + (((size_t)bh) << 16);
  const u16* Vbh = Vt + (((size_t)bh) << 16);

  int soff = wq * 1024 + lane * 8;
  int doff = wq * 1024;

  #pragma unroll
  for (int i = 0; i < 2; i++) {
    load_lds16(Kbh + soff + i*512, &KV[0][0][doff + i*512]);
    load_lds16(Vbh + soff + i*512, &KV[0][1][doff + i*512]);
  }
  asm volatile("s_waitcnt vmcnt(0)" ::: "memory");
  raw_barrier();

  for (int t = 0; t < ntiles; t++) {
    int cur = t & 1;
    if (t + 1 < ntiles) {
      const u16* kn = Kbh + ((size_t)(t+1) << 12);
      const u16* vn = Vbh + ((size_t)(t+1) << 12);
      #pragma unroll
      for (int i = 0; i < 2; i++) {
        load_lds16(kn + soff + i*512, &KV[cur^1][0][doff + i*512]);
        load_lds16(vn + soff + i*512, &KV[cur^1][1][doff + i*512]);
      }
    }
    int kv0 = t << 6;
    if (kv0 < nkv_w) {
      const u16* Kl = &KV[cur][0][0];
      const u16* Vl = &KV[cur][1][0];
      f32x4 sf[4];
      __builtin_amdgcn_s_setprio(1);
      #pragma unroll
      for (int t4 = 0; t4 < 4; t4++) {
        f32x4 s = {0.f, 0.f, 0.f, 0.f};
        int kvl = t4*16 + l15;
        #pragma unroll
        for (int kk = 0; kk < 2; kk++) {
          bf16x8 bk = *reinterpret_cast<const bf16x8*>(&Kl[kvl*64 + ((kk*32 + l4*8) ^ ((l15 & 7) << 3))]);
          s = __builtin_amdgcn_mfma_f32_16x16x32_bf16(aq[kk], bk, s, 0, 0, 0);
        }
        sf[t4] = s * 0.125f;
      }
      __builtin_amdgcn_s_setprio(0);
      if (causal && (kv0 + 63 > q0)) {
        #pragma unroll
        for (int t4 = 0; t4 < 4; t4++) {
          int kvg = kv0 + t4*16 + l15;
          #pragma unroll
          for (int r = 0; r < 4; r++) {
            int qg = q0 + (l4 << 2) + r;
            if (kvg > qg) sf[t4][r] = -INFINITY;
          }
        }
      }
      float pv[4][4];
      #pragma unroll
      for (int r = 0; r < 4; r++) {
        float mx = fmaxf(fmaxf(sf[0][r], sf[1][r]), fmaxf(sf[2][r], sf[3][r]));
        #pragma unroll
        for (int off = 1; off < 16; off <<= 1) mx = fmaxf(mx, __shfl_xor(mx, off, 64));
        float mnew = fmaxf(mrow[r], mx);
        float alpha = __expf(mrow[r] - mnew);
        mrow[r] = mnew;
        float psum = 0.f;
        #pragma unroll
        for (int t4 = 0; t4 < 4; t4++) {
          float p = __expf(sf[t4][r] - mnew);
          pv[t4][r] = p;
          psum += p;
        }
        #pragma unroll
        for (int off = 1; off < 16; off <<= 1) psum += __shfl_xor(psum, off, 64);
        lrow[r] = lrow[r] * alpha + psum;
        #pragma unroll
        for (int h4 = 0; h4 < 4; h4++) acc[h4][r] *= alpha;
      }
      #pragma unroll
      for (int r = 0; r < 4; r++) {
        int ql = l4*4 + r;
        unsigned wA = (unsigned)f2bf(pv[0][r]) | ((unsigned)f2bf(pv[1][r]) << 16);
        unsigned wB = (unsigned)f2bf(pv[2][r]) | ((unsigned)f2bf(pv[3][r]) << 16);
        int xo = (ql & 7) << 2;
        Ps[wq][ql*32 + ((2*l15)     ^ xo)] = wA;
        Ps[wq][ql*32 + ((2*l15 + 1) ^ xo)] = wB;
      }
      __builtin_amdgcn_s_setprio(1);
      #pragma unroll
      for (int h4 = 0; h4 < 4; h4++) {
        int dl = h4*16 + l15;
        #pragma unroll
        for (int kk = 0; kk < 2; kk++) {
          bf16x8 pa = *reinterpret_cast<const bf16x8*>(
              (const u16*)&Ps[wq][0] + l15*64 + ((kk*32 + l4*8) ^ ((l15 & 7) << 3)));
          bf16x8 vb = *reinterpret_cast<const bf16x8*>(&Vl[dl*64 + ((kk*32 + l4*8) ^ ((l15 & 7) << 3))]);
          acc[h4] = __builtin_amdgcn_mfma_f32_16x16x32_bf16(pa, vb, acc[h4], 0, 0, 0);
        }
      }
      __builtin_amdgcn_s_setprio(0);
    }
    asm volatile("s_waitcnt vmcnt(0)" ::: "memory");
    raw_barrier();
  }
  #pragma unroll
  for (int h4 = 0; h4 < 4; h4++) {
    #pragma unroll
    for (int r = 0; r < 4; r++) {
      int row = q0 + (l4 << 2) + r;
      float ov = acc[h4][r] / lrow[r];
      o[(tok0 + row) * 1024 + h * 64 + h4*16 + l15] = f2bf(ov);
    }
  }
}

extern "C" void kernel_launch(void* const* d_in, const int* in_sizes, int n_in,
                              void* d_out, int out_size, void* d_ws, size_t ws_size,
                              hipStream_t stream) {
  (void)in_sizes; (void)n_in; (void)out_size; (void)ws_size;
  const float* sensor = (const float*)d_in[0];
  const float* traj   = (const float*)d_in[1];
  const float* pos    = (const float*)d_in[2];
  const float* ln1_s  = (const float*)d_in[3];
  const float* ln1_b  = (const float*)d_in[4];
  const float* qkv_w  = (const float*)d_in[5];
  const float* qkv_b  = (const float*)d_in[6];
  const float* out_w  = (const float*)d_in[7];
  const float* out_b  = (const float*)d_in[8];
  const float* ln2_s  = (const float*)d_in[9];
  const float* ln2_b  = (const float*)d_in[10];
  const float* w1     = (const float*)d_in[11];
  const float* b1     = (const float*)d_in[12];
  const float* w2     = (const float*)d_in[13];
  const float* b2     = (const float*)d_in[14];
  const float* fln_s  = (const float*)d_in[15];
  const float* fln_b  = (const float*)d_in[16];

  char* ws = (char*)d_ws;
  size_t off = 0;
  float* x  = (float*)(ws + off); off += (size_t)NTOK_ * D_ * 4;
  u16* h    = (u16*)(ws + off);   off += (size_t)NTOK_ * D_ * 2;
  u16* Qb   = (u16*)(ws + off);   off += (size_t)NTOK_ * D_ * 2;
  u16* Ktl  = (u16*)(ws + off);   off += (size_t)NTOK_ * D_ * 2;
  u16* Vtl  = (u16*)(ws + off);   off += (size_t)NTOK_ * D_ * 2;
  u16* ob   = (u16*)(ws + off);   off += (size_t)NTOK_ * D_ * 2;
  u16* ub   = (u16*)(ws + off);   off += (size_t)NTOK_ * FF_ * 2;
  u16* wb   = (u16*)(ws + off);   off += (size_t)(3*D_*D_ + D_*D_ + FF_*D_ + D_*FF_) * 2;
  u16* wqkv = wb;
  u16* wout = wqkv + (size_t)3*D_*D_;
  u16* ww1  = wout + (size_t)D_*D_;
  u16* ww2  = ww1  + (size_t)FF_*D_;

  posadd_kernel<<<NTOK_ * D_ / 1024, 256, 0, stream>>>(sensor, traj, pos, x);

  for (int i = 0; i < NL_; i++) {
    castln_kernel<<<NCAST_ + NTOK_/4, 256, 0, stream>>>(
        qkv_w + (size_t)i*3*D_*D_, out_w + (size_t)i*D_*D_,
        w1 + (size_t)i*FF_*D_, w2 + (size_t)i*D_*FF_, wb,
        x, ln1_s + i*D_, ln1_b + i*D_, h);
    gemm256x128_kernel<3><<<32*24, 512, 0, stream>>>(h, wqkv, qkv_b + (size_t)i*3*D_, Qb, Ktl, Vtl, 3*D_, D_, 32);
    attn_kernel<<<B_*H_*(L_/64), 256, 0, stream>>>(Qb, Ktl, Vtl, ob);
    gemm_kernel<<<64*8, 256, 0, stream>>>(ob, wout, out_b + (size_t)i*D_, x, D_, D_, 64);
    ln_kernel<u16><<<NTOK_/4, 256, 0, stream>>>(x, ln2_s + i*D_, ln2_b + i*D_, h);
    gemm256x128_kernel<1><<<32*32, 512, 0, stream>>>(h, ww1, b1 + (size_t)i*FF_, ub, nullptr, nullptr, FF_, D_, 32);
    gemm_kernel<<<64*8, 256, 0, stream>>>(ub, ww2, b2 + (size_t)i*D_, x, D_, FF_, 64);
  }
  ln_kernel<float><<<NTOK_/4, 256, 0, stream>>>(x, fln_s, fln_b, (float*)d_out);
}